// Round 5
// baseline (349.663 us; speedup 1.0000x reference)
//
#include <hip/hip_runtime.h>
#include <hip/hip_bf16.h>

#define M_DIM 32768
#define K_DIM 1024
#define N_POOL 1024

#define BM 256
#define BN 256
#define BK 64
#define KTILES (K_DIM / BK)   // 16

typedef __attribute__((ext_vector_type(8))) short bf16x8;
typedef __attribute__((ext_vector_type(16))) float f32x16;

typedef __attribute__((address_space(3))) unsigned int lds_uint;
typedef const __attribute__((address_space(1))) unsigned int g_uint;

__device__ __forceinline__ unsigned short f2bf(float f) {
    unsigned int u = __builtin_bit_cast(unsigned int, f);
    unsigned int lsb = (u >> 16) & 1u;
    u += 0x7fffu + lsb;
    return (unsigned short)(u >> 16);
}

__device__ __forceinline__ unsigned int f2bf2(float lo, float hi) {
    __hip_bfloat162 h2 = __float22bfloat162_rn(make_float2(lo, hi));
    union { __hip_bfloat162 h; unsigned int u; } c;
    c.h = h2;
    return c.u;
}

__device__ __forceinline__ float gelu2(float y) {
    // 0.5*y*(1+tanh(GC*(y+0.044715 y^3))) * SCALE(2)
    const float GC = 0.7978845608028654f;
    float z = GC * (y + 0.044715f * y * y * y);
    float e = __expf(2.0f * z);
    return y * (2.0f - 2.0f / (e + 1.0f));
}

// ---------------- prep: fold avgpool(k=4) into weight/bias, cast to bf16 ----
__global__ __launch_bounds__(256) void prep_kernel(
        const float* __restrict__ W, const float* __restrict__ b,
        unsigned short* __restrict__ wp, float* __restrict__ bp) {
    int n = blockIdx.x;
    int t = threadIdx.x;
    const float4* r0 = (const float4*)(W + (size_t)(4 * n + 0) * K_DIM);
    const float4* r1 = (const float4*)(W + (size_t)(4 * n + 1) * K_DIM);
    const float4* r2 = (const float4*)(W + (size_t)(4 * n + 2) * K_DIM);
    const float4* r3 = (const float4*)(W + (size_t)(4 * n + 3) * K_DIM);
    float4 a0 = r0[t], a1 = r1[t], a2 = r2[t], a3 = r3[t];
    float sx = (a0.x + a1.x + a2.x + a3.x) * 0.25f;
    float sy = (a0.y + a1.y + a2.y + a3.y) * 0.25f;
    float sz = (a0.z + a1.z + a2.z + a3.z) * 0.25f;
    float sw = (a0.w + a1.w + a2.w + a3.w) * 0.25f;
    ushort4 h;
    h.x = f2bf(sx); h.y = f2bf(sy); h.z = f2bf(sz); h.w = f2bf(sw);
    *(ushort4*)&wp[(size_t)n * K_DIM + t * 4] = h;
    if (t == 0)
        bp[n] = 0.25f * (b[4 * n] + b[4 * n + 1] + b[4 * n + 2] + b[4 * n + 3]);
}

// ======================= 256x256 4-phase GEMM (32x32x16 MFMA) ===============
// LDS: [r][BK] bf16 rows (128 B), 16B chunk col swizzled: slot = c16 ^ (r&7).
// A: reg-staged (f32 -> cvt_pk -> swizzled ds_write). B: global_load_lds with
// pre-swizzled global source (linear LDS dest), same involution.

__device__ __forceinline__ bf16x8 ldfrag(const unsigned short* base, int r, int c16) {
    return *(const bf16x8*)&base[r * 64 + (((c16) ^ (r & 7)) << 3)];
}

struct AStage { float4 av[8]; };

__device__ __forceinline__ void a_issue(AStage& s, const float4* __restrict__ xg,
                                        int m0, int kc, int tid) {
#pragma unroll
    for (int j = 0; j < 4; ++j) {
        int p = j * 512 + tid;            // 16B-chunk index within tile
        int row = p >> 3, c16 = p & 7;
        size_t base = (size_t)(m0 + row) * 256 + (kc >> 2) + c16 * 2;
        s.av[2 * j]     = xg[base];
        s.av[2 * j + 1] = xg[base + 1];
    }
}

__device__ __forceinline__ void a_write(const AStage& s, unsigned short* An, int tid) {
#pragma unroll
    for (int j = 0; j < 4; ++j) {
        int p = j * 512 + tid;
        int row = p >> 3, c16 = p & 7;
        union { bf16x8 v; unsigned int u[4]; } pk;
        pk.u[0] = f2bf2(s.av[2 * j].x,     s.av[2 * j].y);
        pk.u[1] = f2bf2(s.av[2 * j].z,     s.av[2 * j].w);
        pk.u[2] = f2bf2(s.av[2 * j + 1].x, s.av[2 * j + 1].y);
        pk.u[3] = f2bf2(s.av[2 * j + 1].z, s.av[2 * j + 1].w);
        *(bf16x8*)&An[row * 64 + ((c16 ^ (row & 7)) << 3)] = pk.v;
    }
}

__device__ __forceinline__ void b_issue(const unsigned short* __restrict__ wp,
                                        unsigned short* Bn, int n0, int kc,
                                        int wid, int lane) {
#pragma unroll
    for (int i = 0; i < 4; ++i) {
        int row0 = (wid * 4 + i) * 8;
        int n = n0 + row0 + (lane >> 3);
        int g = (lane & 7) ^ (lane >> 3);   // swizzled source chunk
        __builtin_amdgcn_global_load_lds(
            (g_uint*)(wp + (size_t)n * K_DIM + kc + g * 8),
            (lds_uint*)&Bn[row0 * 64], 16, 0, 0);
    }
}

__global__ __launch_bounds__(512, 2) void gemm_kernel(
        const float* __restrict__ x, const unsigned short* __restrict__ wp,
        const float* __restrict__ bp, float* __restrict__ partial) {
    __shared__ unsigned short As[2][BM * BK];   // 2 x 32 KB
    __shared__ unsigned short Bs[2][BN * BK];   // 2 x 32 KB

    int bid = blockIdx.x;
    int wg = (bid & 7) * 64 + (bid >> 3);   // 512 % 8 == 0 -> bijective
    int nblk = wg & 3;
    int mblk = wg >> 2;
    int m0 = mblk * BM;
    int n0 = nblk * BN;

    int tid = threadIdx.x;
    int lane = tid & 63;
    int wid = tid >> 6;              // 0..7
    int wm = wid >> 2, wn = wid & 3; // 2 x 4 wave grid; wave tile 128x64
    int l31 = lane & 31;
    int khi = lane >> 5;             // 0..1 (k-group within fragment)

    // acc[mf][nf]: mf in 0..3 (32-row frags), nf in 0..1 (32-col frags)
    f32x16 acc[4][2];
#pragma unroll
    for (int i = 0; i < 4; ++i)
#pragma unroll
        for (int j = 0; j < 2; ++j)
            acc[i][j] = (f32x16)(0.0f);

    const float4* xg = (const float4*)x;

    // ---- prologue: stage tile 0 into buf 0, full drain, barrier ----
    {
        AStage sa;
        a_issue(sa, xg, m0, 0, tid);
        b_issue(wp, Bs[0], n0, 0, wid, lane);
        a_write(sa, As[0], tid);
        asm volatile("s_waitcnt vmcnt(0) lgkmcnt(0)" ::: "memory");
        __builtin_amdgcn_sched_barrier(0);
        __builtin_amdgcn_s_barrier();
    }

#pragma unroll 1
    for (int kt = 0; kt < KTILES; ++kt) {
        const int cur = kt & 1;
        const bool stage = (kt + 1) < KTILES;
        const int kc = (kt + 1) * BK;
        const unsigned short* Ac = As[cur];
        const unsigned short* Bc = Bs[cur];
        unsigned short* An = As[cur ^ 1];
        unsigned short* Bn = Bs[cur ^ 1];

        AStage sa;

        // ======== m-half 0 (af held across P0,P1: 8 b128 = 32 regs) ========
        {
            bf16x8 af[2][4];
#pragma unroll
            for (int mf = 0; mf < 2; ++mf)
#pragma unroll
                for (int ks = 0; ks < 4; ++ks)
                    af[mf][ks] = ldfrag(Ac, wm * 128 + mf * 32 + l31, ks * 2 + khi);

            // ---- P0: bf(n-col 0), stage issues, MFMA Q(0,0) ----
            {
                bf16x8 bf[4];
#pragma unroll
                for (int ks = 0; ks < 4; ++ks)
                    bf[ks] = ldfrag(Bc, wn * 64 + l31, ks * 2 + khi);
                if (stage) {
                    a_issue(sa, xg, m0, kc, tid);
                    b_issue(wp, Bn, n0, kc, wid, lane);
                }
                __builtin_amdgcn_s_barrier();
                __builtin_amdgcn_s_setprio(1);
#pragma unroll
                for (int ks = 0; ks < 4; ++ks)
#pragma unroll
                    for (int mf = 0; mf < 2; ++mf)
                        acc[mf][0] = __builtin_amdgcn_mfma_f32_32x32x16_bf16(
                            af[mf][ks], bf[ks], acc[mf][0], 0, 0, 0);
                __builtin_amdgcn_s_setprio(0);
                __builtin_amdgcn_s_barrier();
            }
            // ---- P1: bf(n-col 1), MFMA Q(0,1) ----
            {
                bf16x8 bf[4];
#pragma unroll
                for (int ks = 0; ks < 4; ++ks)
                    bf[ks] = ldfrag(Bc, wn * 64 + 32 + l31, ks * 2 + khi);
                __builtin_amdgcn_s_barrier();
                __builtin_amdgcn_s_setprio(1);
#pragma unroll
                for (int ks = 0; ks < 4; ++ks)
#pragma unroll
                    for (int mf = 0; mf < 2; ++mf)
                        acc[mf][1] = __builtin_amdgcn_mfma_f32_32x32x16_bf16(
                            af[mf][ks], bf[ks], acc[mf][1], 0, 0, 0);
                __builtin_amdgcn_s_setprio(0);
                __builtin_amdgcn_s_barrier();
            }
        }

        // ======== m-half 1 (af reused registers, P2,P3) ========
        {
            bf16x8 af[2][4];
#pragma unroll
            for (int mf = 0; mf < 2; ++mf)
#pragma unroll
                for (int ks = 0; ks < 4; ++ks)
                    af[mf][ks] = ldfrag(Ac, wm * 128 + 64 + mf * 32 + l31, ks * 2 + khi);

            // ---- P2: bf(n-col 0), MFMA Q(1,0) ----
            {
                bf16x8 bf[4];
#pragma unroll
                for (int ks = 0; ks < 4; ++ks)
                    bf[ks] = ldfrag(Bc, wn * 64 + l31, ks * 2 + khi);
                __builtin_amdgcn_s_barrier();
                __builtin_amdgcn_s_setprio(1);
#pragma unroll
                for (int ks = 0; ks < 4; ++ks)
#pragma unroll
                    for (int mf = 0; mf < 2; ++mf)
                        acc[mf + 2][0] = __builtin_amdgcn_mfma_f32_32x32x16_bf16(
                            af[mf][ks], bf[ks], acc[mf + 2][0], 0, 0, 0);
                __builtin_amdgcn_s_setprio(0);
                __builtin_amdgcn_s_barrier();
            }
            // ---- P3: bf(n-col 1), MFMA Q(1,1), A cvt+write, drain ----
            {
                bf16x8 bf[4];
#pragma unroll
                for (int ks = 0; ks < 4; ++ks)
                    bf[ks] = ldfrag(Bc, wn * 64 + 32 + l31, ks * 2 + khi);
                __builtin_amdgcn_s_barrier();
                __builtin_amdgcn_s_setprio(1);
#pragma unroll
                for (int ks = 0; ks < 4; ++ks)
#pragma unroll
                    for (int mf = 0; mf < 2; ++mf)
                        acc[mf + 2][1] = __builtin_amdgcn_mfma_f32_32x32x16_bf16(
                            af[mf][ks], bf[ks], acc[mf + 2][1], 0, 0, 0);
                __builtin_amdgcn_s_setprio(0);
                if (stage)
                    a_write(sa, An, tid);   // compiler waits A-loads (counted)
                asm volatile("s_waitcnt vmcnt(0) lgkmcnt(0)" ::: "memory");
                __builtin_amdgcn_sched_barrier(0);
                __builtin_amdgcn_s_barrier();
            }
        }
    }

    // ---- epilogue: bias + tanh-gelu*2 + row-max (32x32 C layout) ----
    // C/D: col = lane&31, row = (r&3) + 8*(r>>2) + 4*(lane>>5)
    float bv0 = bp[n0 + wn * 64 + l31];
    float bv1 = bp[n0 + wn * 64 + 32 + l31];

#pragma unroll
    for (int mf = 0; mf < 4; ++mf) {
#pragma unroll
        for (int r = 0; r < 16; ++r) {
            float v0 = gelu2(acc[mf][0][r] + bv0);
            float v1 = gelu2(acc[mf][1][r] + bv1);
            float mx = fmaxf(v0, v1);
#pragma unroll
            for (int s = 1; s < 32; s <<= 1)
                mx = fmaxf(mx, __shfl_xor(mx, s, 64));
            if (l31 == 0) {
                int row_local = (r & 3) + 8 * (r >> 2) + 4 * khi;
                int grow = m0 + wm * 128 + mf * 32 + row_local;
                partial[(size_t)(nblk * 4 + wn) * M_DIM + grow] = mx;
            }
        }
    }
}

// ---------------- final reduce: max over 16 column-chunks -------------------
__global__ __launch_bounds__(256) void reduce_kernel(
        const float* __restrict__ partial, float* __restrict__ out) {
    int m = blockIdx.x * 256 + threadIdx.x;
    float mx = -3.4e38f;
#pragma unroll
    for (int c = 0; c < 16; ++c)
        mx = fmaxf(mx, partial[(size_t)c * M_DIM + m]);
    out[m] = mx;
}

extern "C" void kernel_launch(void* const* d_in, const int* in_sizes, int n_in,
                              void* d_out, int out_size, void* d_ws, size_t ws_size,
                              hipStream_t stream) {
    const float* x = (const float*)d_in[0];
    const float* W = (const float*)d_in[1];
    const float* bias = (const float*)d_in[2];
    float* out = (float*)d_out;

    unsigned short* wp = (unsigned short*)d_ws;                         // 2 MB
    float* bp = (float*)((char*)d_ws + 2 * 1024 * 1024);                // 4 KB
    float* partial = (float*)((char*)d_ws + 2 * 1024 * 1024 + 4096);    // 2 MB

    prep_kernel<<<N_POOL, 256, 0, stream>>>(W, bias, wp, bp);
    gemm_kernel<<<(M_DIM / BM) * (N_POOL / BN), 512, 0, stream>>>(x, wp, bp, partial);
    reduce_kernel<<<M_DIM / 256, 256, 0, stream>>>(partial, out);
}

// Round 6
// 154.272 us; speedup vs baseline: 2.2665x; 2.2665x over previous
//
#include <hip/hip_runtime.h>
#include <hip/hip_bf16.h>

#define M_DIM 32768
#define K_DIM 1024
#define N_POOL 1024

#define BM 128
#define BN 128
#define BK 64
#define KTILES (K_DIM / BK)   // 16

typedef __attribute__((ext_vector_type(8))) short bf16x8;
typedef __attribute__((ext_vector_type(4))) float f32x4;

typedef __attribute__((address_space(3))) unsigned int lds_uint;
typedef const __attribute__((address_space(1))) unsigned int g_uint;

__device__ __forceinline__ unsigned short f2bf(float f) {
    unsigned int u = __builtin_bit_cast(unsigned int, f);
    unsigned int lsb = (u >> 16) & 1u;
    u += 0x7fffu + lsb;
    return (unsigned short)(u >> 16);
}

__device__ __forceinline__ unsigned int f2bf2(float lo, float hi) {
    // packed RNE cvt — compiler emits v_cvt_pk_bf16_f32
    __hip_bfloat162 h2 = __float22bfloat162_rn(make_float2(lo, hi));
    union { __hip_bfloat162 h; unsigned int u; } c;
    c.h = h2;
    return c.u;
}

// ---------------- prep: fold avgpool(k=4) into weight/bias, cast to bf16 ----
__global__ __launch_bounds__(256) void prep_kernel(
        const float* __restrict__ W, const float* __restrict__ b,
        unsigned short* __restrict__ wp, float* __restrict__ bp) {
    int n = blockIdx.x;
    int t = threadIdx.x;
    const float4* r0 = (const float4*)(W + (size_t)(4 * n + 0) * K_DIM);
    const float4* r1 = (const float4*)(W + (size_t)(4 * n + 1) * K_DIM);
    const float4* r2 = (const float4*)(W + (size_t)(4 * n + 2) * K_DIM);
    const float4* r3 = (const float4*)(W + (size_t)(4 * n + 3) * K_DIM);
    float4 a0 = r0[t], a1 = r1[t], a2 = r2[t], a3 = r3[t];
    float sx = (a0.x + a1.x + a2.x + a3.x) * 0.25f;
    float sy = (a0.y + a1.y + a2.y + a3.y) * 0.25f;
    float sz = (a0.z + a1.z + a2.z + a3.z) * 0.25f;
    float sw = (a0.w + a1.w + a2.w + a3.w) * 0.25f;
    ushort4 h;
    h.x = f2bf(sx); h.y = f2bf(sy); h.z = f2bf(sz); h.w = f2bf(sw);
    *(ushort4*)&wp[(size_t)n * K_DIM + t * 4] = h;
    if (t == 0)
        bp[n] = 0.25f * (b[4 * n] + b[4 * n + 1] + b[4 * n + 2] + b[4 * n + 3]);
}

// ============== 128x128 double-buffered pipelined GEMM (T3-min recipe) ======
// LDS: [r][BK] bf16 rows (128 B), 16B chunk col swizzled: slot = c16 ^ (r&7).
// A: reg-staged (f32 -> cvt_pk -> swizzled ds_write, write-late T14).
// B: global_load_lds, pre-swizzled global source (linear LDS dest).
// One vmcnt(0)+lgkmcnt(0)+barrier per K-tile; next tile's loads issued before
// current tile's compute so they stay in flight across the whole tile.

struct AStage { float4 av[8]; };

__device__ __forceinline__ void a_issue(AStage& s, const float4* __restrict__ xg,
                                        int m0, int kt, int tid) {
#pragma unroll
    for (int j = 0; j < 4; ++j) {
        int f16 = j * 256 + tid;             // 16B-chunk index in tile (0..1023)
        int r = f16 >> 3, c16 = f16 & 7;
        size_t base = (size_t)(m0 + r) * 256 + kt * 16 + c16 * 2;
        s.av[2 * j]     = xg[base];
        s.av[2 * j + 1] = xg[base + 1];
    }
}

__device__ __forceinline__ void a_write(const AStage& s, unsigned short* An, int tid) {
#pragma unroll
    for (int j = 0; j < 4; ++j) {
        int f16 = j * 256 + tid;
        int r = f16 >> 3, c16 = f16 & 7;
        union { bf16x8 v; unsigned int u[4]; } pk;
        pk.u[0] = f2bf2(s.av[2 * j].x,     s.av[2 * j].y);
        pk.u[1] = f2bf2(s.av[2 * j].z,     s.av[2 * j].w);
        pk.u[2] = f2bf2(s.av[2 * j + 1].x, s.av[2 * j + 1].y);
        pk.u[3] = f2bf2(s.av[2 * j + 1].z, s.av[2 * j + 1].w);
        *(bf16x8*)&An[r * 64 + ((c16 ^ (r & 7)) << 3)] = pk.v;
    }
}

__device__ __forceinline__ void b_issue(const unsigned short* __restrict__ wp,
                                        unsigned short* Bn, int n0, int kt,
                                        int wid, int lane) {
#pragma unroll
    for (int i = 0; i < 4; ++i) {
        int ii = wid * 4 + i;
        int rsub = lane >> 3;
        int g = (lane & 7) ^ rsub;           // swizzled source chunk
        int n = n0 + ii * 8 + rsub;
        __builtin_amdgcn_global_load_lds(
            (g_uint*)(wp + (size_t)n * K_DIM + kt * BK + g * 8),
            (lds_uint*)&Bn[ii * 512], 16, 0, 0);
    }
}

__global__ __launch_bounds__(256, 2) void gemm_kernel(
        const float* __restrict__ x, const unsigned short* __restrict__ wp,
        const float* __restrict__ bp, float* __restrict__ partial) {
    __shared__ unsigned short As[2][BM * BK];   // 2 x 16 KB
    __shared__ unsigned short Bs[2][BN * BK];   // 2 x 16 KB

    // XCD-chunked swizzle: 2048 blocks, 8 XCDs, 256 each (bijective)
    int bid = blockIdx.x;
    int wg = (bid & 7) * 256 + (bid >> 3);
    int nblk = wg & 7;
    int mblk = wg >> 3;
    int m0 = mblk * BM;
    int n0 = nblk * BN;

    int tid = threadIdx.x;
    int lane = tid & 63;
    int wid = tid >> 6;
    int wr = wid >> 1, wc = wid & 1;   // 2x2 wave grid, each wave 64x64

    f32x4 acc[4][4];
#pragma unroll
    for (int i = 0; i < 4; ++i)
#pragma unroll
        for (int j = 0; j < 4; ++j)
            acc[i][j] = (f32x4)(0.0f);

    const float4* xg = (const float4*)x;

    // ---- prologue: stage tile 0 into buf 0, drain, barrier ----
    {
        AStage sa;
        a_issue(sa, xg, m0, 0, tid);
        b_issue(wp, Bs[0], n0, 0, wid, lane);
        a_write(sa, As[0], tid);
        asm volatile("s_waitcnt vmcnt(0) lgkmcnt(0)" ::: "memory");
        __builtin_amdgcn_sched_barrier(0);
        __builtin_amdgcn_s_barrier();
    }

#pragma unroll 1
    for (int kt = 0; kt < KTILES; ++kt) {
        const int cur = kt & 1;
        const bool stage = (kt + 1) < KTILES;
        const unsigned short* Ac = As[cur];
        const unsigned short* Bc = Bs[cur];
        unsigned short* An = As[cur ^ 1];
        unsigned short* Bn = Bs[cur ^ 1];

        // ---- issue next tile's loads FIRST (stay in flight across compute) ----
        AStage sa;
        if (stage) {
            a_issue(sa, xg, m0, kt + 1, tid);    // A first: oldest in vmcnt queue
            b_issue(wp, Bn, n0, kt + 1, wid, lane);
        }

        // ---- compute current tile: 2 x (8 swizzled ds_read_b128 + 16 MFMA) ----
#pragma unroll
        for (int kk = 0; kk < BK; kk += 32) {
            int c16r = (kk >> 3) + (lane >> 4);
            bf16x8 af[4], bff[4];
#pragma unroll
            for (int mi = 0; mi < 4; ++mi) {
                int r = wr * 64 + mi * 16 + (lane & 15);
                af[mi] = *(const bf16x8*)&Ac[r * 64 + ((c16r ^ (r & 7)) << 3)];
            }
#pragma unroll
            for (int ni = 0; ni < 4; ++ni) {
                int r = wc * 64 + ni * 16 + (lane & 15);
                bff[ni] = *(const bf16x8*)&Bc[r * 64 + ((c16r ^ (r & 7)) << 3)];
            }
            __builtin_amdgcn_s_setprio(1);
#pragma unroll
            for (int mi = 0; mi < 4; ++mi)
#pragma unroll
                for (int ni = 0; ni < 4; ++ni)
                    acc[mi][ni] = __builtin_amdgcn_mfma_f32_16x16x32_bf16(
                        af[mi], bff[ni], acc[mi][ni], 0, 0, 0);
            __builtin_amdgcn_s_setprio(0);
        }

        // ---- write-late A stage (compiler waits A-loads only: counted vmcnt) ----
        if (stage)
            a_write(sa, An, tid);

        // ---- single drain + barrier per K-tile ----
        asm volatile("s_waitcnt vmcnt(0) lgkmcnt(0)" ::: "memory");
        __builtin_amdgcn_sched_barrier(0);
        __builtin_amdgcn_s_barrier();
    }

    // ---- epilogue: bias + tanh-gelu*2 + row-max over this 64-col slice ----
    float bv[4];
#pragma unroll
    for (int ni = 0; ni < 4; ++ni)
        bv[ni] = bp[n0 + wc * 64 + ni * 16 + (lane & 15)];

    const float GC = 0.7978845608028654f;
#pragma unroll
    for (int mi = 0; mi < 4; ++mi) {
#pragma unroll
        for (int j = 0; j < 4; ++j) {
            float mx = -3.4e38f;
#pragma unroll
            for (int ni = 0; ni < 4; ++ni) {
                float y = acc[mi][ni][j] + bv[ni];
                float z = GC * (y + 0.044715f * y * y * y);
                float e = __expf(2.0f * z);
                float th = 1.0f - 2.0f / (e + 1.0f);   // tanh(z)
                float g = y * (1.0f + th);             // 0.5*(1+tanh)*y*SCALE(2)
                mx = fmaxf(mx, g);
            }
#pragma unroll
            for (int s = 1; s < 16; s <<= 1)
                mx = fmaxf(mx, __shfl_xor(mx, s, 64));
            if ((lane & 15) == 0) {
                int grow = m0 + wr * 64 + mi * 16 + (lane >> 4) * 4 + j;
                partial[(size_t)(nblk * 2 + wc) * M_DIM + grow] = mx;
            }
        }
    }
}

// ---------------- final reduce: max over 16 column-chunks -------------------
__global__ __launch_bounds__(256) void reduce_kernel(
        const float* __restrict__ partial, float* __restrict__ out) {
    int m = blockIdx.x * 256 + threadIdx.x;
    float mx = -3.4e38f;
#pragma unroll
    for (int c = 0; c < 16; ++c)
        mx = fmaxf(mx, partial[(size_t)c * M_DIM + m]);
    out[m] = mx;
}

extern "C" void kernel_launch(void* const* d_in, const int* in_sizes, int n_in,
                              void* d_out, int out_size, void* d_ws, size_t ws_size,
                              hipStream_t stream) {
    const float* x = (const float*)d_in[0];
    const float* W = (const float*)d_in[1];
    const float* bias = (const float*)d_in[2];
    float* out = (float*)d_out;

    unsigned short* wp = (unsigned short*)d_ws;                         // 2 MB
    float* bp = (float*)((char*)d_ws + 2 * 1024 * 1024);                // 4 KB
    float* partial = (float*)((char*)d_ws + 2 * 1024 * 1024 + 4096);    // 2 MB

    prep_kernel<<<N_POOL, 256, 0, stream>>>(W, bias, wp, bp);
    gemm_kernel<<<(M_DIM / BM) * (N_POOL / BN), 256, 0, stream>>>(x, wp, bp, partial);
    reduce_kernel<<<M_DIM / 256, 256, 0, stream>>>(partial, out);
}

// Round 7
// 152.287 us; speedup vs baseline: 2.2961x; 1.0130x over previous
//
#include <hip/hip_runtime.h>
#include <hip/hip_bf16.h>

#define M_DIM 32768
#define K_DIM 1024
#define N_POOL 1024

#define BM 128
#define BN 128
#define BK 64
#define KTILES (K_DIM / BK)   // 16

typedef __attribute__((ext_vector_type(8))) short bf16x8;
typedef __attribute__((ext_vector_type(4))) float f32x4;

typedef __attribute__((address_space(3))) unsigned int lds_uint;
typedef const __attribute__((address_space(1))) unsigned int g_uint;

__device__ __forceinline__ unsigned short f2bf(float f) {
    unsigned int u = __builtin_bit_cast(unsigned int, f);
    unsigned int lsb = (u >> 16) & 1u;
    u += 0x7fffu + lsb;
    return (unsigned short)(u >> 16);
}

__device__ __forceinline__ unsigned int f2bf2(float lo, float hi) {
    // packed RNE cvt — compiler emits v_cvt_pk_bf16_f32
    __hip_bfloat162 h2 = __float22bfloat162_rn(make_float2(lo, hi));
    union { __hip_bfloat162 h; unsigned int u; } c;
    c.h = h2;
    return c.u;
}

// ---------------- prep: fold avgpool(k=4) into weight/bias, cast to bf16 ----
__global__ __launch_bounds__(256) void prep_kernel(
        const float* __restrict__ W, const float* __restrict__ b,
        unsigned short* __restrict__ wp, float* __restrict__ bp) {
    int n = blockIdx.x;
    int t = threadIdx.x;
    const float4* r0 = (const float4*)(W + (size_t)(4 * n + 0) * K_DIM);
    const float4* r1 = (const float4*)(W + (size_t)(4 * n + 1) * K_DIM);
    const float4* r2 = (const float4*)(W + (size_t)(4 * n + 2) * K_DIM);
    const float4* r3 = (const float4*)(W + (size_t)(4 * n + 3) * K_DIM);
    float4 a0 = r0[t], a1 = r1[t], a2 = r2[t], a3 = r3[t];
    float sx = (a0.x + a1.x + a2.x + a3.x) * 0.25f;
    float sy = (a0.y + a1.y + a2.y + a3.y) * 0.25f;
    float sz = (a0.z + a1.z + a2.z + a3.z) * 0.25f;
    float sw = (a0.w + a1.w + a2.w + a3.w) * 0.25f;
    ushort4 h;
    h.x = f2bf(sx); h.y = f2bf(sy); h.z = f2bf(sz); h.w = f2bf(sw);
    *(ushort4*)&wp[(size_t)n * K_DIM + t * 4] = h;
    if (t == 0)
        bp[n] = 0.25f * (b[4 * n] + b[4 * n + 1] + b[4 * n + 2] + b[4 * n + 3]);
}

// ======== 128x128 GEMM: R2 structure + issue-early/write-late A + B-dbuf ====
// LDS: [r][BK] bf16 rows (128 B), 16B chunk col swizzled: slot = c16 ^ (r&7).
// As single-buffered (rewritten in the short serial region from registers);
// Bs double-buffered (glds issued at compute start, lands during compute).

struct AStage { float4 av[8]; };

__device__ __forceinline__ void a_issue(AStage& s, const float4* __restrict__ xg,
                                        int m0, int kt, int tid) {
#pragma unroll
    for (int j = 0; j < 4; ++j) {
        int f16 = j * 256 + tid;             // 16B-chunk index in tile (0..1023)
        int r = f16 >> 3, c16 = f16 & 7;
        size_t base = (size_t)(m0 + r) * 256 + kt * 16 + c16 * 2;
        s.av[2 * j]     = xg[base];
        s.av[2 * j + 1] = xg[base + 1];
    }
}

__device__ __forceinline__ void a_write(const AStage& s, unsigned short* An, int tid) {
#pragma unroll
    for (int j = 0; j < 4; ++j) {
        int f16 = j * 256 + tid;
        int r = f16 >> 3, c16 = f16 & 7;
        union { bf16x8 v; unsigned int u[4]; } pk;
        pk.u[0] = f2bf2(s.av[2 * j].x,     s.av[2 * j].y);
        pk.u[1] = f2bf2(s.av[2 * j].z,     s.av[2 * j].w);
        pk.u[2] = f2bf2(s.av[2 * j + 1].x, s.av[2 * j + 1].y);
        pk.u[3] = f2bf2(s.av[2 * j + 1].z, s.av[2 * j + 1].w);
        *(bf16x8*)&An[r * 64 + ((c16 ^ (r & 7)) << 3)] = pk.v;
    }
}

__device__ __forceinline__ void b_issue(const unsigned short* __restrict__ wp,
                                        unsigned short* Bn, int n0, int kt,
                                        int wid, int lane) {
#pragma unroll
    for (int i = 0; i < 4; ++i) {
        int ii = wid * 4 + i;
        int rsub = lane >> 3;
        int g = (lane & 7) ^ rsub;           // swizzled source chunk
        int n = n0 + ii * 8 + rsub;
        __builtin_amdgcn_global_load_lds(
            (g_uint*)(wp + (size_t)n * K_DIM + kt * BK + g * 8),
            (lds_uint*)&Bn[ii * 512], 16, 0, 0);
    }
}

__global__ __launch_bounds__(256, 2) void gemm_kernel(
        const float* __restrict__ x, const unsigned short* __restrict__ wp,
        const float* __restrict__ bp, float* __restrict__ partial) {
    __shared__ unsigned short As[BM * BK];      // 16 KB, single-buffered
    __shared__ unsigned short Bs[2][BN * BK];   // 2 x 16 KB

    // XCD-chunked swizzle: 2048 blocks, 8 XCDs, 256 each (bijective)
    int bid = blockIdx.x;
    int wg = (bid & 7) * 256 + (bid >> 3);
    int nblk = wg & 7;
    int mblk = wg >> 3;
    int m0 = mblk * BM;
    int n0 = nblk * BN;

    int tid = threadIdx.x;
    int lane = tid & 63;
    int wid = tid >> 6;
    int wr = wid >> 1, wc = wid & 1;   // 2x2 wave grid, each wave 64x64

    f32x4 acc[4][4];
#pragma unroll
    for (int i = 0; i < 4; ++i)
#pragma unroll
        for (int j = 0; j < 4; ++j)
            acc[i][j] = (f32x4)(0.0f);

    const float4* xg = (const float4*)x;

    // ---- prologue: stage tile 0 (A regs->LDS, B glds->Bs[0]), drain ----
    {
        AStage sa;
        a_issue(sa, xg, m0, 0, tid);
        b_issue(wp, Bs[0], n0, 0, wid, lane);
        a_write(sa, As, tid);
        asm volatile("s_waitcnt vmcnt(0) lgkmcnt(0)" ::: "memory");
        __builtin_amdgcn_sched_barrier(0);
        __builtin_amdgcn_s_barrier();
    }

#pragma unroll 1
    for (int kt = 0; kt < KTILES; ++kt) {
        const int cur = kt & 1;
        const bool stage = (kt + 1) < KTILES;
        const unsigned short* Bc = Bs[cur];
        unsigned short* Bn = Bs[cur ^ 1];

        // ---- issue next tile's loads FIRST: latency hides under compute ----
        AStage sa;
        if (stage) {
            a_issue(sa, xg, m0, kt + 1, tid);    // f32 A -> regs (oldest in queue)
            b_issue(wp, Bn, n0, kt + 1, wid, lane);  // bf16 B -> Bs[cur^1]
        }

        // ---- compute current tile: 2 x (8 swizzled ds_read_b128 + 16 MFMA) ----
#pragma unroll
        for (int kk = 0; kk < BK; kk += 32) {
            int c16r = (kk >> 3) + (lane >> 4);
            bf16x8 af[4], bff[4];
#pragma unroll
            for (int mi = 0; mi < 4; ++mi) {
                int r = wr * 64 + mi * 16 + (lane & 15);
                af[mi] = *(const bf16x8*)&As[r * 64 + ((c16r ^ (r & 7)) << 3)];
            }
#pragma unroll
            for (int ni = 0; ni < 4; ++ni) {
                int r = wc * 64 + ni * 16 + (lane & 15);
                bff[ni] = *(const bf16x8*)&Bc[r * 64 + ((c16r ^ (r & 7)) << 3)];
            }
            __builtin_amdgcn_s_setprio(1);
#pragma unroll
            for (int mi = 0; mi < 4; ++mi)
#pragma unroll
                for (int ni = 0; ni < 4; ++ni)
                    acc[mi][ni] = __builtin_amdgcn_mfma_f32_16x16x32_bf16(
                        af[mi], bff[ni], acc[mi][ni], 0, 0, 0);
            __builtin_amdgcn_s_setprio(0);
        }

        // ---- short serial region: all waves done reading As, rewrite it ----
        __builtin_amdgcn_s_barrier();            // raw: ds_reads are data-complete
        if (stage)
            a_write(sa, As, tid);                // cvt_pk + 4 ds_write_b128 only
        asm volatile("s_waitcnt vmcnt(0) lgkmcnt(0)" ::: "memory");
        __builtin_amdgcn_sched_barrier(0);
        __builtin_amdgcn_s_barrier();
    }

    // ---- epilogue: bias + tanh-gelu*2 + row-max over this 64-col slice ----
    float bv[4];
#pragma unroll
    for (int ni = 0; ni < 4; ++ni)
        bv[ni] = bp[n0 + wc * 64 + ni * 16 + (lane & 15)];

    const float GC = 0.7978845608028654f;
#pragma unroll
    for (int mi = 0; mi < 4; ++mi) {
#pragma unroll
        for (int j = 0; j < 4; ++j) {
            float mx = -3.4e38f;
#pragma unroll
            for (int ni = 0; ni < 4; ++ni) {
                float y = acc[mi][ni][j] + bv[ni];
                float z = GC * (y + 0.044715f * y * y * y);
                float e = __expf(2.0f * z);
                float th = 1.0f - 2.0f / (e + 1.0f);   // tanh(z)
                float g = y * (1.0f + th);             // 0.5*(1+tanh)*y*SCALE(2)
                mx = fmaxf(mx, g);
            }
#pragma unroll
            for (int s = 1; s < 16; s <<= 1)
                mx = fmaxf(mx, __shfl_xor(mx, s, 64));
            if ((lane & 15) == 0) {
                int grow = m0 + wr * 64 + mi * 16 + (lane >> 4) * 4 + j;
                partial[(size_t)(nblk * 2 + wc) * M_DIM + grow] = mx;
            }
        }
    }
}

// ---------------- final reduce: max over 16 column-chunks -------------------
__global__ __launch_bounds__(256) void reduce_kernel(
        const float* __restrict__ partial, float* __restrict__ out) {
    int m = blockIdx.x * 256 + threadIdx.x;
    float mx = -3.4e38f;
#pragma unroll
    for (int c = 0; c < 16; ++c)
        mx = fmaxf(mx, partial[(size_t)c * M_DIM + m]);
    out[m] = mx;
}

extern "C" void kernel_launch(void* const* d_in, const int* in_sizes, int n_in,
                              void* d_out, int out_size, void* d_ws, size_t ws_size,
                              hipStream_t stream) {
    const float* x = (const float*)d_in[0];
    const float* W = (const float*)d_in[1];
    const float* bias = (const float*)d_in[2];
    float* out = (float*)d_out;

    unsigned short* wp = (unsigned short*)d_ws;                         // 2 MB
    float* bp = (float*)((char*)d_ws + 2 * 1024 * 1024);                // 4 KB
    float* partial = (float*)((char*)d_ws + 2 * 1024 * 1024 + 4096);    // 2 MB

    prep_kernel<<<N_POOL, 256, 0, stream>>>(W, bias, wp, bp);
    gemm_kernel<<<(M_DIM / BM) * (N_POOL / BN), 256, 0, stream>>>(x, wp, bp, partial);
    reduce_kernel<<<M_DIM / 256, 256, 0, stream>>>(partial, out);
}

// Round 8
// 134.556 us; speedup vs baseline: 2.5986x; 1.1318x over previous
//
#include <hip/hip_runtime.h>
#include <hip/hip_bf16.h>

#define M_DIM 32768
#define K_DIM 1024
#define N_POOL 1024

#define BM 128
#define BN 128
#define BK 32
#define KTILES (K_DIM / BK)   // 32

typedef __attribute__((ext_vector_type(8))) short bf16x8;
typedef __attribute__((ext_vector_type(4))) float f32x4;

typedef __attribute__((address_space(3))) unsigned int lds_uint;
typedef const __attribute__((address_space(1))) unsigned int g_uint;

__device__ __forceinline__ unsigned short f2bf(float f) {
    unsigned int u = __builtin_bit_cast(unsigned int, f);
    unsigned int lsb = (u >> 16) & 1u;
    u += 0x7fffu + lsb;
    return (unsigned short)(u >> 16);
}

__device__ __forceinline__ unsigned int f2bf2(float lo, float hi) {
    // packed RNE cvt — compiler emits v_cvt_pk_bf16_f32
    __hip_bfloat162 h2 = __float22bfloat162_rn(make_float2(lo, hi));
    union { __hip_bfloat162 h; unsigned int u; } c;
    c.h = h2;
    return c.u;
}

// ---------------- prep: fold avgpool(k=4) into weight/bias, cast to bf16 ----
__global__ __launch_bounds__(256) void prep_kernel(
        const float* __restrict__ W, const float* __restrict__ b,
        unsigned short* __restrict__ wp, float* __restrict__ bp) {
    int n = blockIdx.x;
    int t = threadIdx.x;
    const float4* r0 = (const float4*)(W + (size_t)(4 * n + 0) * K_DIM);
    const float4* r1 = (const float4*)(W + (size_t)(4 * n + 1) * K_DIM);
    const float4* r2 = (const float4*)(W + (size_t)(4 * n + 2) * K_DIM);
    const float4* r3 = (const float4*)(W + (size_t)(4 * n + 3) * K_DIM);
    float4 a0 = r0[t], a1 = r1[t], a2 = r2[t], a3 = r3[t];
    float sx = (a0.x + a1.x + a2.x + a3.x) * 0.25f;
    float sy = (a0.y + a1.y + a2.y + a3.y) * 0.25f;
    float sz = (a0.z + a1.z + a2.z + a3.z) * 0.25f;
    float sw = (a0.w + a1.w + a2.w + a3.w) * 0.25f;
    ushort4 h;
    h.x = f2bf(sx); h.y = f2bf(sy); h.z = f2bf(sz); h.w = f2bf(sw);
    *(ushort4*)&wp[(size_t)n * K_DIM + t * 4] = h;
    if (t == 0)
        bp[n] = 0.25f * (b[4 * n] + b[4 * n + 1] + b[4 * n + 2] + b[4 * n + 3]);
}

// ================= 128x128 GEMM, BK=32, R2 structure =================
// LDS layout (A and B): 2 semantic rows packed per 128B LDS line.
// 16B-slot(r, c16) = (r>>1)*8 + ((((r&1)<<2) | c16) ^ ((r>>1)&7)),  c16 in 0..3.
// Verified 2 lanes/bank (free) for frag reads and ds_writes.
// B staged via global_load_lds with source pre-permuted by the same involution.

__device__ __forceinline__ bf16x8 ldfrag(const unsigned short* base, int r, int c16) {
    int slot = ((r >> 1) << 3) + ((((r & 1) << 2) | c16) ^ ((r >> 1) & 7));
    return *(const bf16x8*)&base[slot * 8];
}

struct AStage { float4 av[4]; };

__device__ __forceinline__ void a_issue(AStage& s, const float4* __restrict__ xg,
                                        int m0, int kt, int tid) {
    int r = tid >> 1;                     // row 0..127
    int cpair = (tid & 1) * 2;            // chunks {0,1} or {2,3}
    size_t base = (size_t)(m0 + r) * 256 + kt * 8 + cpair * 2;   // float4 units
#pragma unroll
    for (int j = 0; j < 4; ++j)
        s.av[j] = xg[base + j];
}

__device__ __forceinline__ void a_write(const AStage& s, unsigned short* As, int tid) {
    int r = tid >> 1;
    int cpair = (tid & 1) * 2;
#pragma unroll
    for (int h = 0; h < 2; ++h) {
        int c = cpair + h;
        union { bf16x8 v; unsigned int u[4]; } pk;
        pk.u[0] = f2bf2(s.av[2 * h].x,     s.av[2 * h].y);
        pk.u[1] = f2bf2(s.av[2 * h].z,     s.av[2 * h].w);
        pk.u[2] = f2bf2(s.av[2 * h + 1].x, s.av[2 * h + 1].y);
        pk.u[3] = f2bf2(s.av[2 * h + 1].z, s.av[2 * h + 1].w);
        int slot = ((r >> 1) << 3) + ((((r & 1) << 2) | c) ^ ((r >> 1) & 7));
        *(bf16x8*)&As[slot * 8] = pk.v;
    }
}

__device__ __forceinline__ void b_issue(const unsigned short* __restrict__ wp,
                                        unsigned short* Bs, int n0, int kt,
                                        int wid, int lane) {
#pragma unroll
    for (int i = 0; i < 2; ++i) {
        int g = wid * 2 + i;                 // 16-row group, 0..7
        int R = lane >> 3;                   // dest LDS line within group
        int Cp = (lane & 7) ^ (R & 7);       // unswizzled combined chunk
        int n = g * 16 + R * 2 + (Cp >> 2);  // semantic B row
        int c16 = Cp & 3;                    // semantic 16B chunk
        __builtin_amdgcn_global_load_lds(
            (g_uint*)(wp + (size_t)(n0 + n) * K_DIM + kt * BK + c16 * 8),
            (lds_uint*)&Bs[g * 16 * BK], 16, 0, 0);
    }
}

__global__ __launch_bounds__(256, 2) void gemm_kernel(
        const float* __restrict__ x, const unsigned short* __restrict__ wp,
        const float* __restrict__ bp, float* __restrict__ partial) {
    __shared__ unsigned short As[BM * BK];   // 8 KB
    __shared__ unsigned short Bs[BN * BK];   // 8 KB

    // XCD-chunked swizzle: 2048 blocks, 8 XCDs, 256 each (bijective)
    int bid = blockIdx.x;
    int wg = (bid & 7) * 256 + (bid >> 3);
    int nblk = wg & 7;
    int mblk = wg >> 3;
    int m0 = mblk * BM;
    int n0 = nblk * BN;

    int tid = threadIdx.x;
    int lane = tid & 63;
    int wid = tid >> 6;
    int wr = wid >> 1, wc = wid & 1;   // 2x2 wave grid, each wave 64x64

    f32x4 acc[4][4];
#pragma unroll
    for (int i = 0; i < 4; ++i)
#pragma unroll
        for (int j = 0; j < 4; ++j)
            acc[i][j] = (f32x4)(0.0f);

    const float4* xg = (const float4*)x;

#pragma unroll 1
    for (int kt = 0; kt < KTILES; ++kt) {
        __syncthreads();   // previous tile's LDS reads done
        // ---- stage: B glds (pre-swizzled source) + A f32->reg->cvt->LDS ----
        b_issue(wp, Bs, n0, kt, wid, lane);
        AStage sa;
        a_issue(sa, xg, m0, kt, tid);
        a_write(sa, As, tid);
        __syncthreads();   // drains vmcnt (glds) + lgkmcnt (ds_write)

        // ---- compute: 8 swizzled ds_read_b128 + 16 MFMA ----
        int c16 = lane >> 4;             // 0..3 (k-chunk of 8 elems)
        bf16x8 af[4], bff[4];
#pragma unroll
        for (int mi = 0; mi < 4; ++mi)
            af[mi] = ldfrag(As, wr * 64 + mi * 16 + (lane & 15), c16);
#pragma unroll
        for (int ni = 0; ni < 4; ++ni)
            bff[ni] = ldfrag(Bs, wc * 64 + ni * 16 + (lane & 15), c16);
        __builtin_amdgcn_s_setprio(1);
#pragma unroll
        for (int mi = 0; mi < 4; ++mi)
#pragma unroll
            for (int ni = 0; ni < 4; ++ni)
                acc[mi][ni] = __builtin_amdgcn_mfma_f32_16x16x32_bf16(
                    af[mi], bff[ni], acc[mi][ni], 0, 0, 0);
        __builtin_amdgcn_s_setprio(0);
    }

    // ---- epilogue: bias + tanh-gelu*2 + row-max over this 64-col slice ----
    float bv[4];
#pragma unroll
    for (int ni = 0; ni < 4; ++ni)
        bv[ni] = bp[n0 + wc * 64 + ni * 16 + (lane & 15)];

    const float GC = 0.7978845608028654f;
#pragma unroll
    for (int mi = 0; mi < 4; ++mi) {
#pragma unroll
        for (int j = 0; j < 4; ++j) {
            float mx = -3.4e38f;
#pragma unroll
            for (int ni = 0; ni < 4; ++ni) {
                float y = acc[mi][ni][j] + bv[ni];
                float z = GC * (y + 0.044715f * y * y * y);
                float e = __expf(2.0f * z);
                float th = 1.0f - 2.0f / (e + 1.0f);   // tanh(z)
                float g = y * (1.0f + th);             // 0.5*(1+tanh)*y*SCALE(2)
                mx = fmaxf(mx, g);
            }
#pragma unroll
            for (int s = 1; s < 16; s <<= 1)
                mx = fmaxf(mx, __shfl_xor(mx, s, 64));
            if ((lane & 15) == 0) {
                int grow = m0 + wr * 64 + mi * 16 + (lane >> 4) * 4 + j;
                partial[(size_t)(nblk * 2 + wc) * M_DIM + grow] = mx;
            }
        }
    }
}

// ---------------- final reduce: max over 16 column-chunks -------------------
__global__ __launch_bounds__(256) void reduce_kernel(
        const float* __restrict__ partial, float* __restrict__ out) {
    int m = blockIdx.x * 256 + threadIdx.x;
    float mx = -3.4e38f;
#pragma unroll
    for (int c = 0; c < 16; ++c)
        mx = fmaxf(mx, partial[(size_t)c * M_DIM + m]);
    out[m] = mx;
}

extern "C" void kernel_launch(void* const* d_in, const int* in_sizes, int n_in,
                              void* d_out, int out_size, void* d_ws, size_t ws_size,
                              hipStream_t stream) {
    const float* x = (const float*)d_in[0];
    const float* W = (const float*)d_in[1];
    const float* bias = (const float*)d_in[2];
    float* out = (float*)d_out;

    unsigned short* wp = (unsigned short*)d_ws;                         // 2 MB
    float* bp = (float*)((char*)d_ws + 2 * 1024 * 1024);                // 4 KB
    float* partial = (float*)((char*)d_ws + 2 * 1024 * 1024 + 4096);    // 2 MB

    prep_kernel<<<N_POOL, 256, 0, stream>>>(W, bias, wp, bp);
    gemm_kernel<<<(M_DIM / BM) * (N_POOL / BN), 256, 0, stream>>>(x, wp, bp, partial);
    reduce_kernel<<<M_DIM / 256, 256, 0, stream>>>(partial, out);
}